// Round 2
// baseline (313.852 us; speedup 1.0000x reference)
//
#include <hip/hip_runtime.h>

// Problem constants
#define MDIM 8192
#define IDIM 1024
#define ODIM 1024
#define D1   9            // DEGREE+1
#define KDIM (IDIM * D1)  // 9216, k = d*1024 + i ordering

typedef _Float16 half8   __attribute__((ext_vector_type(8)));
typedef _Float16 half2v  __attribute__((ext_vector_type(2)));
typedef float    float4v __attribute__((ext_vector_type(4)));

#define BSCALE 256.0f     // pre-scale B into f16-normal range (exact pow2)
#define INV_BSCALE (1.0f / 256.0f)
#define USCALE 5.123105625617661f    // sqrt(17) + 1
#define H0C 0.7511255444649425f      // pi^-1/4
#define H1C 1.0622519497598084f      // sqrt(2) * pi^-1/4

// ---------------------------------------------------------------------------
// hermite9 (fp32) — used only by the naive fallback.
// ---------------------------------------------------------------------------
__device__ __forceinline__ void hermite9(float xv, float h[D1]) {
    float ax = fabsf(xv);
    float t  = __expf(-2.0f * ax);
    float th = (1.0f - t) / (1.0f + t);
    th = copysignf(th, xv);
    float u = th * USCALE;
    float g = __expf(-0.5f * u * u);
    h[0] = H0C * g;
    h[1] = H1C * u * g;
    const float c1[D1] = {0.f, 0.f, 1.0f, 0.8164965809277260f, 0.7071067811865476f,
                          0.6324555320336759f, 0.5773502691896258f, 0.5345224838248488f, 0.5f};
    const float c2[D1] = {0.f, 0.f, 0.7071067811865476f, 0.8164965809277260f, 0.8660254037844386f,
                          0.8944271909999159f, 0.9128709291752769f, 0.9258200997725514f, 0.9354143466934853f};
#pragma unroll
    for (int d = 2; d < D1; ++d) h[d] = c1[d] * u * h[d - 1] - c2[d] * h[d - 2];
}

// ---------------------------------------------------------------------------
// prep_b v2: LDS transpose. Tile = 32 i x 32 o.
// Read phase: coalesced fp32 along the contiguous (o,d) dim (288 floats/row).
// LDS [od][i] padded to 33 -> conflict-free both phases.
// Write phase: 32 consecutive i per (o,d) = 64B coalesced f16 stores.
// ---------------------------------------------------------------------------
__global__ __launch_bounds__(256) void prep_b(const float* __restrict__ C,
                                              _Float16* __restrict__ Bt) {
    __shared__ float lds[288 * 33];   // 38 KB
    const int t  = threadIdx.x;
    const int ti = blockIdx.x & 31;   // i-tile
    const int to = blockIdx.x >> 5;   // o-tile
    const float* base = C + (size_t)ti * 32 * 9216 + (size_t)to * 32 * 9;
#pragma unroll
    for (int j = 0; j < 36; ++j) {
        int f   = t + 256 * j;        // 0..9215
        int row = f / 288;            // i_local
        int col = f - row * 288;      // o_local*9 + d
        lds[col * 33 + row] = base[(size_t)row * 9216 + col];
    }
    __syncthreads();
    _Float16* bb = Bt + (size_t)to * 32 * KDIM + ti * 32;
#pragma unroll
    for (int j = 0; j < 36; ++j) {
        int e   = t + 256 * j;
        int i   = e & 31;
        int odp = e >> 5;             // 0..287
        int ol  = odp / 9;
        int d   = odp - ol * 9;
        bb[(size_t)ol * KDIM + d * IDIM + i] = (_Float16)(lds[odp * 33 + i] * BSCALE);
    }
}

// ---------------------------------------------------------------------------
// gemm_fused: y = H(x) @ Bt^T with H generated on the fly.
// 128x128 tile, 256 thr (4 waves 2x2), 16x16x32 f16 MFMA, fp32 accum.
// K-loop reordered as (i-block outer, d inner); the h_d 128x64 A-tile is
// produced in-registers via the packed-f16 Hermite recurrence and written
// into the XOR-swizzled As layout (ds_write_b128, conflict-free).
// Bs staged via global_load_lds width=16, issued before the hermite VALU
// so the DMA overlaps compute.
// ---------------------------------------------------------------------------
__global__ __launch_bounds__(256, 2) void gemm_fused(
    const float* __restrict__ x,       // [8192][1024] fp32
    const _Float16* __restrict__ Bt,   // [ODIM][KDIM], pre-scaled by 256
    float* __restrict__ out)           // [8192][ODIM]
{
    const int tid = threadIdx.x;
    const int w = tid >> 6;       // wave 0..3
    const int l = tid & 63;       // lane
    const int bn = blockIdx.x;    // n-tile 0..7
    const int bm = blockIdx.y;    // m-tile 0..63

    __shared__ _Float16 As[128 * 64];
    __shared__ _Float16 Bs[128 * 64];

    // Bs staging: lane l, rep rr loads 16B; stored kgrp = (l&7)^(l>>3) (XOR swizzle)
    const int lrow8 = l >> 3;
    const int kgrp  = (l & 7) ^ lrow8;
    const _Float16* Bg = Bt + ((size_t)(bn * 128 + w * 8 + lrow8) * KDIM + kgrp * 8);

    // compute-side fragment indices
    const int q   = l >> 4;
    const int m16 = l & 15;
    const int s3  = m16 & 7;
    const int wm  = w >> 1, wn = w & 1;

    // hermite producer indices: 2 threads per A-row, 32 i's each
    const int r  = tid >> 1;      // As row 0..127
    const int ih = tid & 1;       // i-half
    const int r7 = r & 7;
    _Float16* arow = As + r * 64;

    float4v acc[4][4] = {};

    constexpr float c1a[D1] = {0.f, 0.f, 1.0f, 0.8164965809277260f, 0.7071067811865476f,
                               0.6324555320336759f, 0.5773502691896258f, 0.5345224838248488f, 0.5f};
    constexpr float c2a[D1] = {0.f, 0.f, 0.7071067811865476f, 0.8164965809277260f, 0.8660254037844386f,
                               0.8944271909999159f, 0.9128709291752769f, 0.9258200997725514f, 0.9354143466934853f};

    for (int ib = 0; ib < 16; ++ib) {
        const int kbase = ib * 64;

        // kick off Bs DMA for d=0 so it overlaps the hermite init below
#pragma unroll
        for (int rr = 0; rr < 4; ++rr)
            __builtin_amdgcn_global_load_lds(
                (const __attribute__((address_space(1))) void*)(Bg + (size_t)(rr * 32) * KDIM + kbase),
                (__attribute__((address_space(3))) void*)((char*)Bs + (rr * 4 + w) * 1024),
                16, 0, 0);

        // load this thread's 32 x values, squash to u
        const float4* xp = (const float4*)(x + (((size_t)(bm * 128 + r)) << 10) + kbase + ih * 32);
        float u[32];
#pragma unroll
        for (int j = 0; j < 8; ++j) {
            float4 v = xp[j];
            u[4*j+0] = v.x; u[4*j+1] = v.y; u[4*j+2] = v.z; u[4*j+3] = v.w;
        }
#pragma unroll
        for (int j = 0; j < 32; ++j) {
            float xv = u[j];
            float t2 = __expf(-2.0f * fabsf(xv));
            float th = (1.0f - t2) / (1.0f + t2);
            u[j] = copysignf(th, xv) * USCALE;
        }
        half2v u2[16], hA[16], hB[16];
#pragma unroll
        for (int p = 0; p < 16; ++p) {
            float u0 = u[2*p], u1 = u[2*p+1];
            float g0 = __expf(-0.5f * u0 * u0);
            float g1 = __expf(-0.5f * u1 * u1);
            u2[p] = half2v{(_Float16)u0, (_Float16)u1};
            hA[p] = half2v{(_Float16)(H0C * g0), (_Float16)(H0C * g1)};
            hB[p] = half2v{(_Float16)(H1C * u0 * g0), (_Float16)(H1C * u1 * g1)};
        }

#pragma unroll
        for (int d = 0; d < D1; ++d) {
            if (d >= 1) {   // d=0 DMA already in flight
#pragma unroll
                for (int rr = 0; rr < 4; ++rr)
                    __builtin_amdgcn_global_load_lds(
                        (const __attribute__((address_space(1))) void*)(Bg + (size_t)(rr * 32) * KDIM + d * IDIM + kbase),
                        (__attribute__((address_space(3))) void*)((char*)Bs + (rr * 4 + w) * 1024),
                        16, 0, 0);
            }
            // pick/advance h_d (packed f16 recurrence)
            half2v ht[16];
            if (d == 0) {
#pragma unroll
                for (int p = 0; p < 16; ++p) ht[p] = hA[p];
            } else if (d == 1) {
#pragma unroll
                for (int p = 0; p < 16; ++p) ht[p] = hB[p];
            } else {
                const half2v c1v = half2v{(_Float16)c1a[d], (_Float16)c1a[d]};
                const half2v c2v = half2v{(_Float16)c2a[d], (_Float16)c2a[d]};
#pragma unroll
                for (int p = 0; p < 16; ++p) {
                    half2v t = u2[p] * hB[p];
                    ht[p] = c1v * t - c2v * hA[p];
                    hA[p] = hB[p];
                    hB[p] = ht[p];
                }
            }
            // write As fragments: 4x 16B per thread, swizzled slots, conflict-free
#pragma unroll
            for (int c = 0; c < 4; ++c) {
                int slot = (ih * 4 + c) ^ r7;
                half8 vv;
#pragma unroll
                for (int pp = 0; pp < 4; ++pp) {
                    vv[2*pp+0] = ht[4*c+pp][0];
                    vv[2*pp+1] = ht[4*c+pp][1];
                }
                *(half8*)(arow + slot * 8) = vv;
            }
            __syncthreads();   // drains ds_write (lgkm) + global_load_lds (vm)

#pragma unroll
            for (int ko = 0; ko < 2; ++ko) {
                const int slot = (q + 4 * ko) ^ s3;
                half8 af[4], bf[4];
#pragma unroll
                for (int i = 0; i < 4; ++i) {
                    af[i] = *(const half8*)&As[(wm * 64 + i * 16 + m16) * 64 + slot * 8];
                    bf[i] = *(const half8*)&Bs[(wn * 64 + i * 16 + m16) * 64 + slot * 8];
                }
#pragma unroll
                for (int i = 0; i < 4; ++i)
#pragma unroll
                    for (int j = 0; j < 4; ++j)
                        acc[i][j] = __builtin_amdgcn_mfma_f32_16x16x32_f16(af[i], bf[j], acc[i][j], 0, 0, 0);
            }
            __syncthreads();   // tiles consumed; next step may overwrite
        }
    }

    // epilogue: D row = quad*4 + reg, col = lane&15 (m89-verified layout)
#pragma unroll
    for (int i = 0; i < 4; ++i) {
        int row = bm * 128 + wm * 64 + i * 16 + q * 4;
#pragma unroll
        for (int j = 0; j < 4; ++j) {
            int col = bn * 128 + wn * 64 + j * 16 + m16;
            float* op = out + (size_t)row * ODIM + col;
#pragma unroll
            for (int r2 = 0; r2 < 4; ++r2)
                op[(size_t)r2 * ODIM] = acc[i][j][r2] * INV_BSCALE;
        }
    }
}

// ---------------------------------------------------------------------------
// naive fallback (only if workspace can't hold Bt, 18.9 MB)
// ---------------------------------------------------------------------------
__global__ void naive_kernel(const float* __restrict__ x, const float* __restrict__ C,
                             float* __restrict__ out) {
    __shared__ float hb[IDIM * D1];   // 36 KB
    int b = blockIdx.x;
    int tid = threadIdx.x;
    for (int i = tid; i < IDIM; i += 256) {
        float h[D1];
        hermite9(x[(size_t)b * IDIM + i], h);
#pragma unroll
        for (int d = 0; d < D1; ++d) hb[i * D1 + d] = h[d];
    }
    __syncthreads();
    for (int o = tid; o < ODIM; o += 256) {
        float acc = 0.f;
        for (int i = 0; i < IDIM; ++i) {
            const float* cp = C + ((size_t)i * ODIM + o) * D1;
            const float* hp = hb + i * D1;
#pragma unroll
            for (int d = 0; d < D1; ++d) acc += hp[d] * cp[d];
        }
        out[(size_t)b * ODIM + o] = acc;
    }
}

// ---------------------------------------------------------------------------
extern "C" void kernel_launch(void* const* d_in, const int* in_sizes, int n_in,
                              void* d_out, int out_size, void* d_ws, size_t ws_size,
                              hipStream_t stream) {
    const float* x      = (const float*)d_in[0];   // [8192][1024]
    const float* coeffs = (const float*)d_in[1];   // [1024][1024][9]
    float* out = (float*)d_out;                    // [8192][1024]

    const size_t bt_bytes = (size_t)ODIM * KDIM * sizeof(_Float16);  // 18.9 MB

    if (ws_size >= bt_bytes) {
        _Float16* Bt = (_Float16*)d_ws;
        hipLaunchKernelGGL(prep_b, dim3(1024), dim3(256), 0, stream, coeffs, Bt);
        hipLaunchKernelGGL(gemm_fused, dim3(8, 64), dim3(256), 0, stream, x, Bt, out);
    } else {
        hipLaunchKernelGGL(naive_kernel, dim3(MDIM), dim3(256), 0, stream, x, coeffs, out);
    }
}

// Round 3
// 281.128 us; speedup vs baseline: 1.1164x; 1.1164x over previous
//
#include <hip/hip_runtime.h>

// Problem constants
#define MDIM 8192
#define IDIM 1024
#define ODIM 1024
#define D1   9            // DEGREE+1
#define KDIM (IDIM * D1)  // 9216, k = d*1024 + i ordering

typedef _Float16 half8   __attribute__((ext_vector_type(8)));
typedef _Float16 half2v  __attribute__((ext_vector_type(2)));
typedef float    float4v __attribute__((ext_vector_type(4)));

#define BSCALE 256.0f     // pre-scale B into f16-normal range (exact pow2)
#define INV_BSCALE (1.0f / 256.0f)
#define USCALE 5.123105625617661f    // sqrt(17) + 1
#define H0C 0.7511255444649425f     // pi^-1/4
#define SQRT2 1.4142135623730951f   // h1 = sqrt2 * u * h0

// ---------------------------------------------------------------------------
// hermite9 (fp32) — naive fallback only.
// ---------------------------------------------------------------------------
__device__ __forceinline__ void hermite9(float xv, float h[D1]) {
    float ax = fabsf(xv);
    float t  = __expf(-2.0f * ax);
    float th = (1.0f - t) / (1.0f + t);
    th = copysignf(th, xv);
    float u = th * USCALE;
    float g = __expf(-0.5f * u * u);
    h[0] = H0C * g;
    h[1] = SQRT2 * H0C * u * g;
    const float c1[D1] = {0.f, 0.f, 1.0f, 0.8164965809277260f, 0.7071067811865476f,
                          0.6324555320336759f, 0.5773502691896258f, 0.5345224838248488f, 0.5f};
    const float c2[D1] = {0.f, 0.f, 0.7071067811865476f, 0.8164965809277260f, 0.8660254037844386f,
                          0.8944271909999159f, 0.9128709291752769f, 0.9258200997725514f, 0.9354143466934853f};
#pragma unroll
    for (int d = 2; d < D1; ++d) h[d] = c1[d] * u * h[d - 1] - c2[d] * h[d - 2];
}

// ---------------------------------------------------------------------------
// prep_b v2: LDS transpose, 32i x 32o tile, padded LDS, coalesced both phases.
// ---------------------------------------------------------------------------
__global__ __launch_bounds__(256) void prep_b(const float* __restrict__ C,
                                              _Float16* __restrict__ Bt) {
    __shared__ float lds[288 * 33];
    const int t  = threadIdx.x;
    const int ti = blockIdx.x & 31;
    const int to = blockIdx.x >> 5;
    const float* base = C + (size_t)ti * 32 * 9216 + (size_t)to * 32 * 9;
#pragma unroll
    for (int j = 0; j < 36; ++j) {
        int f   = t + 256 * j;
        int row = f / 288;
        int col = f - row * 288;
        lds[col * 33 + row] = base[(size_t)row * 9216 + col];
    }
    __syncthreads();
    _Float16* bb = Bt + (size_t)to * 32 * KDIM + ti * 32;
#pragma unroll
    for (int j = 0; j < 36; ++j) {
        int e   = t + 256 * j;
        int i   = e & 31;
        int odp = e >> 5;
        int ol  = odp / 9;
        int d   = odp - ol * 9;
        bb[(size_t)ol * KDIM + d * IDIM + i] = (_Float16)(lds[odp * 33 + i] * BSCALE);
    }
}

// ---------------------------------------------------------------------------
// prep_u: x fp32 -> u = USCALE*tanh(x) and h0 = pi^-1/4 * exp(-u^2/2), both f16.
// Kills the tanh/exp from the GEMM (it was recomputed 8x there).
// ---------------------------------------------------------------------------
__global__ __launch_bounds__(256) void prep_u(const float* __restrict__ x,
                                              _Float16* __restrict__ U,
                                              _Float16* __restrict__ H0) {
    size_t t = (size_t)blockIdx.x * 256 + threadIdx.x;
    const float4* xp = (const float4*)(x + t * 8);
    float4 a0 = xp[0], a1 = xp[1];
    float xv[8] = {a0.x, a0.y, a0.z, a0.w, a1.x, a1.y, a1.z, a1.w};
    half8 uu, hh;
#pragma unroll
    for (int e = 0; e < 8; ++e) {
        float v  = xv[e];
        float t2 = __expf(-2.0f * fabsf(v));
        float th = (1.0f - t2) / (1.0f + t2);
        float u  = copysignf(th, v) * USCALE;
        float g  = __expf(-0.5f * u * u);
        uu[e] = (_Float16)u;
        hh[e] = (_Float16)(H0C * g);
    }
    *(half8*)(U  + t * 8) = uu;
    *(half8*)(H0 + t * 8) = hh;
}

// ---------------------------------------------------------------------------
// gemm_fused2: software-pipelined. Double-buffered As (hermite recurrence
// producer, ds_write_b128) and Bs (global_load_lds DMA), ONE barrier per
// k-step. At step s: MFMA consumes buf[cur] while ht(s+1) is computed in
// VGPRs (separate pipe, no dependence) and DMA fills Bs[nxt].
// 128x128 tile, 4 waves 2x2, 16x16x32 f16 MFMA, XOR-swizzled LDS (0 conflicts).
// ---------------------------------------------------------------------------
__global__ __launch_bounds__(256, 2) void gemm_fused2(
    const _Float16* __restrict__ U,    // [8192][1024] f16
    const _Float16* __restrict__ H0,   // [8192][1024] f16
    const _Float16* __restrict__ Bt,   // [ODIM][KDIM], pre-scaled by 256
    float* __restrict__ out)           // [8192][ODIM]
{
    const int tid = threadIdx.x;
    const int w = tid >> 6;
    const int l = tid & 63;
    const int bn = blockIdx.x;    // n-tile 0..7
    const int bm = blockIdx.y;    // m-tile 0..63

    __shared__ _Float16 As[2][128 * 64];
    __shared__ _Float16 Bs[2][128 * 64];

    // Bs staging: lane l, rep rr loads 16B; stored kgrp = (l&7)^(l>>3)
    const int lrow8 = l >> 3;
    const int kgrp  = (l & 7) ^ lrow8;
    const _Float16* Bg = Bt + ((size_t)(bn * 128 + w * 8 + lrow8) * KDIM + kgrp * 8);

    // compute-side fragment indices
    const int q   = l >> 4;
    const int m16 = l & 15;
    const int s3  = m16 & 7;
    const int wm  = w >> 1, wn = w & 1;

    // hermite producer: 2 threads per A-row, 32 i's each
    const int r  = tid >> 1;
    const int ih = tid & 1;
    const int r7 = r & 7;
    const size_t urow = (((size_t)(bm * 128 + r)) << 10) + ih * 32;

    constexpr float c1a[D1] = {0.f, 0.f, 1.0f, 0.8164965809277260f, 0.7071067811865476f,
                               0.6324555320336759f, 0.5773502691896258f, 0.5345224838248488f, 0.5f};
    constexpr float c2a[D1] = {0.f, 0.f, 0.7071067811865476f, 0.8164965809277260f, 0.8660254037844386f,
                               0.8944271909999159f, 0.9128709291752769f, 0.9258200997725514f, 0.9354143466934853f};

    half2v u2[16], hA[16], hB[16];
    const half2v sq2 = half2v{(_Float16)SQRT2, (_Float16)SQRT2};

    // helper: load u/h0 for i-block kb, set u2/hA, hB = sqrt2*u*h0
    auto loadUH = [&](int kb) {
        const half8* up = (const half8*)(U  + urow + kb);
        const half8* hp = (const half8*)(H0 + urow + kb);
        half8 ub[4], hb[4];
#pragma unroll
        for (int a = 0; a < 4; ++a) { ub[a] = up[a]; hb[a] = hp[a]; }
#pragma unroll
        for (int a = 0; a < 4; ++a)
#pragma unroll
            for (int b = 0; b < 4; ++b) {
                u2[4*a+b] = half2v{ub[a][2*b], ub[a][2*b+1]};
                hA[4*a+b] = half2v{hb[a][2*b], hb[a][2*b+1]};
            }
#pragma unroll
        for (int p = 0; p < 16; ++p) hB[p] = sq2 * u2[p] * hA[p];
    };

    // helper: write 32 ht values into As[buf] row r, XOR-swizzled
    _Float16* arow0 = &As[0][r * 64];
    _Float16* arow1 = &As[1][r * 64];
    auto writeA = [&](int buf, const half2v ht[16]) {
        _Float16* arow = buf ? arow1 : arow0;
#pragma unroll
        for (int c = 0; c < 4; ++c) {
            int slot = (ih * 4 + c) ^ r7;
            half8 vv;
#pragma unroll
            for (int pp = 0; pp < 4; ++pp) {
                vv[2*pp+0] = ht[4*c+pp][0];
                vv[2*pp+1] = ht[4*c+pp][1];
            }
            *(half8*)(arow + slot * 8) = vv;
        }
    };

    float4v acc[4][4] = {};

    // ---- prologue: DMA Bs[0] (d=0, ib=0), produce As[0] = h0
#pragma unroll
    for (int rr = 0; rr < 4; ++rr)
        __builtin_amdgcn_global_load_lds(
            (const __attribute__((address_space(1))) void*)(Bg + (size_t)(rr * 32) * KDIM),
            (__attribute__((address_space(3))) void*)((char*)&Bs[0][0] + (rr * 4 + w) * 1024),
            16, 0, 0);
    loadUH(0);
    writeA(0, hA);
    __syncthreads();

    for (int ib = 0; ib < 16; ++ib) {
        const int kbase = ib * 64;
#pragma unroll
        for (int d = 0; d < D1; ++d) {
            const int cur = (ib + d) & 1;   // step parity ((ib*9+d)&1, 9 odd)
            const int nxt = cur ^ 1;
            const bool has_next = (d < 8) || (ib < 15);

            // A) DMA next step's Bs tile
            if (has_next) {
                const int nkoff = (d == 8) ? (kbase + 64)            // (ib+1, d=0)
                                           : ((d + 1) * IDIM + kbase);
#pragma unroll
                for (int rr = 0; rr < 4; ++rr)
                    __builtin_amdgcn_global_load_lds(
                        (const __attribute__((address_space(1))) void*)(Bg + (size_t)(rr * 32) * KDIM + nkoff),
                        (__attribute__((address_space(3))) void*)((char*)&Bs[nxt][0] + (rr * 4 + w) * 1024),
                        16, 0, 0);
            }

            // B) produce ht for next step (pure VGPR work, overlaps MFMA pipe)
            half2v ht[16];
            if (has_next) {
                if (d == 8) {
                    loadUH(kbase + 64);     // new i-block: reload u/h0, h1
#pragma unroll
                    for (int p = 0; p < 16; ++p) ht[p] = hA[p];   // h0
                } else if (d == 0) {
#pragma unroll
                    for (int p = 0; p < 16; ++p) ht[p] = hB[p];   // h1
                } else {
                    const half2v c1v = half2v{(_Float16)c1a[d+1], (_Float16)c1a[d+1]};
                    const half2v c2v = half2v{(_Float16)c2a[d+1], (_Float16)c2a[d+1]};
#pragma unroll
                    for (int p = 0; p < 16; ++p) {
                        half2v t = u2[p] * hB[p];
                        ht[p] = c1v * t - c2v * hA[p];
                        hA[p] = hB[p];
                        hB[p] = ht[p];
                    }
                }
            }

            // C) MFMA on buf[cur]
#pragma unroll
            for (int ko = 0; ko < 2; ++ko) {
                const int slot = (q + 4 * ko) ^ s3;
                half8 af[4], bf[4];
#pragma unroll
                for (int i = 0; i < 4; ++i) {
                    af[i] = *(const half8*)&As[cur][(wm * 64 + i * 16 + m16) * 64 + slot * 8];
                    bf[i] = *(const half8*)&Bs[cur][(wn * 64 + i * 16 + m16) * 64 + slot * 8];
                }
#pragma unroll
                for (int i = 0; i < 4; ++i)
#pragma unroll
                    for (int j = 0; j < 4; ++j)
                        acc[i][j] = __builtin_amdgcn_mfma_f32_16x16x32_f16(af[i], bf[j], acc[i][j], 0, 0, 0);
            }

            // D) publish next A-tile
            if (has_next) writeA(nxt, ht);

            // E) single barrier: drains ds_write (lgkm) + DMA (vm); also
            //    guarantees buf[cur] fully consumed before step+1 overwrites it
            __syncthreads();
        }
    }

    // epilogue: D row = quad*4 + reg, col = lane&15 (m89-verified layout)
#pragma unroll
    for (int i = 0; i < 4; ++i) {
        int row = bm * 128 + wm * 64 + i * 16 + q * 4;
#pragma unroll
        for (int j = 0; j < 4; ++j) {
            int col = bn * 128 + wn * 64 + j * 16 + m16;
            float* op = out + (size_t)row * ODIM + col;
#pragma unroll
            for (int r2 = 0; r2 < 4; ++r2)
                op[(size_t)r2 * ODIM] = acc[i][j][r2] * INV_BSCALE;
        }
    }
}

// ---------------------------------------------------------------------------
// naive fallback (only if workspace can't hold Bt + U + H0, 52.4 MB)
// ---------------------------------------------------------------------------
__global__ void naive_kernel(const float* __restrict__ x, const float* __restrict__ C,
                             float* __restrict__ out) {
    __shared__ float hb[IDIM * D1];
    int b = blockIdx.x;
    int tid = threadIdx.x;
    for (int i = tid; i < IDIM; i += 256) {
        float h[D1];
        hermite9(x[(size_t)b * IDIM + i], h);
#pragma unroll
        for (int d = 0; d < D1; ++d) hb[i * D1 + d] = h[d];
    }
    __syncthreads();
    for (int o = tid; o < ODIM; o += 256) {
        float acc = 0.f;
        for (int i = 0; i < IDIM; ++i) {
            const float* cp = C + ((size_t)i * ODIM + o) * D1;
            const float* hp = hb + i * D1;
#pragma unroll
            for (int d = 0; d < D1; ++d) acc += hp[d] * cp[d];
        }
        out[(size_t)b * ODIM + o] = acc;
    }
}

// ---------------------------------------------------------------------------
extern "C" void kernel_launch(void* const* d_in, const int* in_sizes, int n_in,
                              void* d_out, int out_size, void* d_ws, size_t ws_size,
                              hipStream_t stream) {
    const float* x      = (const float*)d_in[0];   // [8192][1024]
    const float* coeffs = (const float*)d_in[1];   // [1024][1024][9]
    float* out = (float*)d_out;                    // [8192][1024]

    const size_t bt_bytes = (size_t)ODIM * KDIM * sizeof(_Float16);   // 18.9 MB
    const size_t u_bytes  = (size_t)MDIM * IDIM * sizeof(_Float16);   // 16.8 MB

    if (ws_size >= bt_bytes + 2 * u_bytes) {
        _Float16* Bt = (_Float16*)d_ws;
        _Float16* Uv = (_Float16*)((char*)d_ws + bt_bytes);
        _Float16* H0 = (_Float16*)((char*)d_ws + bt_bytes + u_bytes);
        hipLaunchKernelGGL(prep_b, dim3(1024), dim3(256), 0, stream, coeffs, Bt);
        hipLaunchKernelGGL(prep_u, dim3((MDIM * IDIM) / 2048), dim3(256), 0, stream, x, Uv, H0);
        hipLaunchKernelGGL(gemm_fused2, dim3(8, 64), dim3(256), 0, stream, Uv, H0, Bt, out);
    } else {
        hipLaunchKernelGGL(naive_kernel, dim3(MDIM), dim3(256), 0, stream, x, coeffs, out);
    }
}